// Round 8
// baseline (2906.831 us; speedup 1.0000x reference)
//
#include <hip/hip_runtime.h>
#include <stdint.h>
#include <math.h>

typedef unsigned long long u64;
typedef float f32x2 __attribute__((ext_vector_type(2)));

#define NROW 12288
#define DFEAT 512
#define HDIM  1024
#define NB    96   // NROW/128

// ==================================================================================
// NUMERICS CONTRACT (validated round 9, absmax 1.95e-3):
//   - every GEMM C element = single-accumulator FMA chain, k ascending, in panels
//     (512) for K=512 and (512,512) for K=1024, panels merged with one f32 add;
//   - norm = numpy classic pairwise (unchanged);
//   - top-32: exact byte-radix select (same selected SET as u64-key pop loop);
//     0.5v+0.5v symmetric scatter unchanged.
// Round 8: v_pk_fma_f32 inner loops (f32x2 + __builtin_elementwise_fma — two
// INDEPENDENT IEEE fmas per instruction; each element keeps its own chain, k
// ascending -> bit-identical). gemmsym restored to lb(256,4), no reg-prefetch
// (r7 lesson: TLP already hides staging latency; prefetch cost occupancy).
// MLP back to 3-launch NPANEL=2 in-register panels. Plain zero. r7 topk kept.
// ==================================================================================

// ---------------- MLP GEMM: 128x128 tile, 8x8/thread, pk-fma ----------
// MODE 0: store relu(v + bias)      (h1, h2)
// MODE 1: store resid + (v + bias)  (feat = X + h)
// NPANEL: 1 -> K=512 single chain; 2 -> K=1024 chains (512,512) merged with one add.
template <int MODE, int NPANEL>
__global__ __launch_bounds__(256, 3) void gemm128(
    const float* __restrict__ A, const float* __restrict__ B,
    const float* __restrict__ bias, const float* __restrict__ resid,
    float* __restrict__ C, int Nn, int K)
{
  __shared__ float As[32][128];   // [k][m], XOR-swizzled m-groups, no pad
  __shared__ float Bs[32][128];   // [k][n]
  const int t = threadIdx.x;
  const int tn = t & 15, tm = t >> 4;
  const size_t m0 = (size_t)blockIdx.y * 128, n0 = (size_t)blockIdx.x * 128;

  f32x2 cur[2][2][4][2] = {};             // [ih][jh][i][jpair]
  f32x2 tot[2][2][4][2];                  // used only when NPANEL==2

  for (int kt = 0; kt < K; kt += 32) {
#pragma unroll
    for (int u = 0; u < 4; ++u) {
      int f = u * 256 + t;
      int r = f >> 3, c = f & 7;
      int pm = (r & 3) + 4 * ((r >> 2) ^ c);   // swizzled m-slot (bijective per k-row)
      float4 va = *(const float4*)(A + (m0 + r) * (size_t)K + kt + 4 * c);
      As[4 * c + 0][pm] = va.x; As[4 * c + 1][pm] = va.y;
      As[4 * c + 2][pm] = va.z; As[4 * c + 3][pm] = va.w;
      float4 vb = *(const float4*)(B + (n0 + r) * (size_t)K + kt + 4 * c);
      Bs[4 * c + 0][pm] = vb.x; Bs[4 * c + 1][pm] = vb.y;
      Bs[4 * c + 2][pm] = vb.z; Bs[4 * c + 3][pm] = vb.w;
    }
    __syncthreads();
#pragma unroll 4
    for (int kk = 0; kk < 32; ++kk) {
      const int key = kk >> 2;
      float4 a0 = *(const float4*)&As[kk][4 * (tm ^ key)];
      float4 a1 = *(const float4*)&As[kk][4 * (16 + (tm ^ key))];
      float4 b0 = *(const float4*)&Bs[kk][4 * (tn ^ key)];
      float4 b1 = *(const float4*)&Bs[kk][4 * (16 + (tn ^ key))];
      float av[2][4] = {{a0.x, a0.y, a0.z, a0.w}, {a1.x, a1.y, a1.z, a1.w}};
      f32x2 bv[2][2] = {{{b0.x, b0.y}, {b0.z, b0.w}},
                        {{b1.x, b1.y}, {b1.z, b1.w}}};
#pragma unroll
      for (int ih = 0; ih < 2; ++ih)
#pragma unroll
        for (int jh = 0; jh < 2; ++jh)
#pragma unroll
          for (int i = 0; i < 4; ++i)
#pragma unroll
            for (int jp = 0; jp < 2; ++jp) {
              f32x2 aa = {av[ih][i], av[ih][i]};
              cur[ih][jh][i][jp] =
                  __builtin_elementwise_fma(aa, bv[jh][jp], cur[ih][jh][i][jp]);
            }
    }
    __syncthreads();
    if (NPANEL == 2) {
      int ke = kt + 32;
      if (ke == 512) {          // first panel ends: move, restart chain
#pragma unroll
        for (int ih = 0; ih < 2; ++ih)
#pragma unroll
          for (int jh = 0; jh < 2; ++jh)
#pragma unroll
            for (int i = 0; i < 4; ++i)
#pragma unroll
              for (int jp = 0; jp < 2; ++jp) {
                tot[ih][jh][i][jp] = cur[ih][jh][i][jp];
                cur[ih][jh][i][jp] = (f32x2){0.f, 0.f};
              }
      }
    }
  }
  // final value: NPANEL==1 -> cur; NPANEL==2 -> tot + cur (one add, left-assoc)
#pragma unroll
  for (int ih = 0; ih < 2; ++ih)
#pragma unroll
    for (int i = 0; i < 4; ++i) {
      size_t gm = m0 + 64 * ih + 4 * tm + i;
#pragma unroll
      for (int jh = 0; jh < 2; ++jh) {
        size_t gn = n0 + 64 * jh + 4 * tn;
        float rv[4];
#pragma unroll
        for (int j = 0; j < 4; ++j) {
          float cv = cur[ih][jh][i][j >> 1][j & 1];
          float v = (NPANEL == 2) ? (tot[ih][jh][i][j >> 1][j & 1] + cv) : cv;
          v = v + bias[gn + j];
          if (MODE == 0) {
            v = v > 0.f ? v : 0.f;
          } else {
            v = resid[gm * (size_t)Nn + gn + j] + v;
          }
          rv[j] = v;
        }
        float4 res = {rv[0], rv[1], rv[2], rv[3]};
        *(float4*)(C + gm * (size_t)Nn + gn) = res;
      }
    }
}

// ---------------- symmetric sim GEMM: upper-tri blocks, pk-fma -------------------
__global__ __launch_bounds__(256, 4) void gemmsym(
    const float* __restrict__ F, float* __restrict__ C)
{
  __shared__ float As[32][128];
  __shared__ float Bs[32][128];
  const int t = threadIdx.x;
  const int tn = t & 15, tm = t >> 4;

  // decode linear block -> (bi, bj), bi<=bj; S(b) = b*NB - b*(b-1)/2
  int lin = blockIdx.x;
  int bi = (int)(NB + 0.5 - sqrt((NB + 0.5) * (NB + 0.5) - 2.0 * (double)lin));
  if (bi < 0) bi = 0;
  if (bi > NB - 1) bi = NB - 1;
  while (bi + 1 <= NB - 1 && (bi + 1) * NB - ((bi + 1) * bi) / 2 <= lin) ++bi;
  while (bi * NB - (bi * (bi - 1)) / 2 > lin) --bi;
  int bj = bi + (lin - (bi * NB - (bi * (bi - 1)) / 2));

  const size_t m0 = (size_t)bi * 128, n0 = (size_t)bj * 128;

  f32x2 cur[2][2][4][2] = {};

  for (int kt = 0; kt < DFEAT; kt += 32) {
#pragma unroll
    for (int u = 0; u < 4; ++u) {
      int f = u * 256 + t;
      int r = f >> 3, c = f & 7;
      int pm = (r & 3) + 4 * ((r >> 2) ^ c);
      float4 va = *(const float4*)(F + (m0 + r) * (size_t)DFEAT + kt + 4 * c);
      As[4 * c + 0][pm] = va.x; As[4 * c + 1][pm] = va.y;
      As[4 * c + 2][pm] = va.z; As[4 * c + 3][pm] = va.w;
      float4 vb = *(const float4*)(F + (n0 + r) * (size_t)DFEAT + kt + 4 * c);
      Bs[4 * c + 0][pm] = vb.x; Bs[4 * c + 1][pm] = vb.y;
      Bs[4 * c + 2][pm] = vb.z; Bs[4 * c + 3][pm] = vb.w;
    }
    __syncthreads();
#pragma unroll 4
    for (int kk = 0; kk < 32; ++kk) {
      const int key = kk >> 2;
      float4 a0 = *(const float4*)&As[kk][4 * (tm ^ key)];
      float4 a1 = *(const float4*)&As[kk][4 * (16 + (tm ^ key))];
      float4 b0 = *(const float4*)&Bs[kk][4 * (tn ^ key)];
      float4 b1 = *(const float4*)&Bs[kk][4 * (16 + (tn ^ key))];
      float av[2][4] = {{a0.x, a0.y, a0.z, a0.w}, {a1.x, a1.y, a1.z, a1.w}};
      f32x2 bv[2][2] = {{{b0.x, b0.y}, {b0.z, b0.w}},
                        {{b1.x, b1.y}, {b1.z, b1.w}}};
#pragma unroll
      for (int ih = 0; ih < 2; ++ih)
#pragma unroll
        for (int jh = 0; jh < 2; ++jh)
#pragma unroll
          for (int i = 0; i < 4; ++i)
#pragma unroll
            for (int jp = 0; jp < 2; ++jp) {
              f32x2 aa = {av[ih][i], av[ih][i]};
              cur[ih][jh][i][jp] =
                  __builtin_elementwise_fma(aa, bv[jh][jp], cur[ih][jh][i][jp]);
            }
    }
    __syncthreads();
  }

  // relu in place
#pragma unroll
  for (int ih = 0; ih < 2; ++ih)
#pragma unroll
    for (int jh = 0; jh < 2; ++jh)
#pragma unroll
      for (int i = 0; i < 4; ++i)
#pragma unroll
        for (int jp = 0; jp < 2; ++jp) {
          f32x2 v = cur[ih][jh][i][jp];
          v[0] = v[0] > 0.f ? v[0] : 0.f;
          v[1] = v[1] > 0.f ? v[1] : 0.f;
          cur[ih][jh][i][jp] = v;
        }

  // normal tile write (coalesced)
#pragma unroll
  for (int ih = 0; ih < 2; ++ih)
#pragma unroll
    for (int i = 0; i < 4; ++i) {
      size_t gm = m0 + 64 * ih + 4 * tm + i;
#pragma unroll
      for (int jh = 0; jh < 2; ++jh) {
        float4 res = {cur[ih][jh][i][0][0], cur[ih][jh][i][0][1],
                      cur[ih][jh][i][1][0], cur[ih][jh][i][1][1]};
        *(float4*)(C + gm * (size_t)NROW + n0 + 64 * jh + 4 * tn) = res;
      }
    }
  // mirrored tile write (skip on diagonal blocks)
  if (bi != bj) {
#pragma unroll
    for (int jh = 0; jh < 2; ++jh)
#pragma unroll
      for (int j = 0; j < 4; ++j) {
        size_t gn = n0 + 64 * jh + 4 * tn + j;
#pragma unroll
        for (int ih = 0; ih < 2; ++ih) {
          float4 res = {cur[ih][jh][0][j >> 1][j & 1], cur[ih][jh][1][j >> 1][j & 1],
                        cur[ih][jh][2][j >> 1][j & 1], cur[ih][jh][3][j >> 1][j & 1]};
          *(float4*)(C + gn * (size_t)NROW + m0 + 64 * ih + 4 * tm) = res;
        }
      }
  }
}

// ---------------- norm + fn: numpy classic pairwise (UNCHANGED, bit-critical) -----
__global__ __launch_bounds__(256) void norm_fn_kernel(const float* __restrict__ feat,
                                                      float* __restrict__ fn) {
#pragma clang fp contract(off)
  const int row = blockIdx.x * 4 + (threadIdx.x >> 6);
  const int lane = threadIdx.x & 63;
  const float* fr = feat + (size_t)row * DFEAT;
  float r = 0.f;
  if (lane < 32) {
    const float* bp = fr + (lane >> 3) * 128 + (lane & 7);
    float x = bp[0];
    r = x * x;
#pragma unroll
    for (int i = 8; i <= 120; i += 8) {
      float x2 = bp[i];
      float s = x2 * x2;
      r = r + s;
    }
  }
  float v[32];
#pragma unroll
  for (int j = 0; j < 32; ++j) v[j] = __shfl(r, j);
  float Bv[4];
#pragma unroll
  for (int b = 0; b < 4; ++b) {
    const float* p = v + 8 * b;
    Bv[b] = ((p[0] + p[1]) + (p[2] + p[3])) + ((p[4] + p[5]) + (p[6] + p[7]));
  }
  float S = (Bv[0] + Bv[1]) + (Bv[2] + Bv[3]);
  float den = (float)sqrt((double)S) + 1e-8f;
#pragma unroll
  for (int e = 0; e < 8; ++e) {
    int d = e * 64 + lane;
    fn[(size_t)row * DFEAT + d] = fr[d] / den;
  }
}

// ---------------- per-row top-32: exact byte-radix select (r7, privatized) -------
__device__ __forceinline__ void radix_scan(const unsigned int (*h4)[256], int* st, int t) {
  if (t < 64) {
    int h0 = (int)(h4[0][4 * t + 0] + h4[1][4 * t + 0] + h4[2][4 * t + 0] + h4[3][4 * t + 0]);
    int h1 = (int)(h4[0][4 * t + 1] + h4[1][4 * t + 1] + h4[2][4 * t + 1] + h4[3][4 * t + 1]);
    int h2 = (int)(h4[0][4 * t + 2] + h4[1][4 * t + 2] + h4[2][4 * t + 2] + h4[3][4 * t + 2]);
    int h3 = (int)(h4[0][4 * t + 3] + h4[1][4 * t + 3] + h4[2][4 * t + 3] + h4[3][4 * t + 3]);
    int S = h0 + h1 + h2 + h3;
#pragma unroll
    for (int off = 1; off < 64; off <<= 1) {
      int o = __shfl_down(S, off);
      if (t + off < 64) S += o;
    }
    int Sn = __shfl_down(S, 1);
    if (t == 63) Sn = 0;
    int needed = st[1];
    if (S >= needed && Sn < needed) {
      int cg = Sn, b;
      if (cg + h3 >= needed) b = 3;
      else if ((cg += h3) + h2 >= needed) b = 2;
      else if ((cg += h2) + h1 >= needed) b = 1;
      else { cg += h1; b = 0; }
      st[0] = (st[0] << 8) | (4 * t + b);
      st[1] = needed - cg;
    }
    if (t == 0 && S < needed) { st[2] = 1; st[1] = needed - S; }
  }
}

__global__ __launch_bounds__(256, 3) void topk_kernel(
    const float* __restrict__ sim, float* __restrict__ topv, int* __restrict__ topi)
{
  __shared__ __align__(16) unsigned int svb[NROW];  // 48 KiB: row value bits
  __shared__ unsigned int hist4[4][256];            // per-wave histograms
  __shared__ int st[4];
  __shared__ int smin[4];
  const int row = blockIdx.x, t = threadIdx.x;
  const float4* rp = (const float4*)(sim + (size_t)row * NROW);
  unsigned int* myh = hist4[t >> 6];

#pragma unroll
  for (int w = 0; w < 4; ++w) hist4[w][t] = 0;
  if (t == 0) { st[0] = 0; st[1] = 32; st[2] = 0; st[3] = 0; }
  __syncthreads();

#pragma unroll
  for (int it = 0; it < 12; ++it) {
    int q = t + 256 * it;
    float4 v = rp[q];
    unsigned w0 = __float_as_uint(v.x), w1 = __float_as_uint(v.y),
             w2 = __float_as_uint(v.z), w3 = __float_as_uint(v.w);
    uint4 u; u.x = w0; u.y = w1; u.z = w2; u.w = w3;
    *(uint4*)&svb[4 * q] = u;
    if (w0) atomicAdd(&myh[w0 >> 24], 1u);
    if (w1) atomicAdd(&myh[w1 >> 24], 1u);
    if (w2) atomicAdd(&myh[w2 >> 24], 1u);
    if (w3) atomicAdd(&myh[w3 >> 24], 1u);
  }
  __syncthreads();
  radix_scan(hist4, st, t);
  __syncthreads();

  for (int p = 1; p < 4; ++p) {
    if (st[2]) break;
    unsigned pref = (unsigned)st[0];
    const int sh = 24 - 8 * p;
#pragma unroll
    for (int w = 0; w < 4; ++w) hist4[w][t] = 0;
    __syncthreads();
#pragma unroll
    for (int it = 0; it < 12; ++it) {
      uint4 u = *(const uint4*)&svb[4 * (t + 256 * it)];
      unsigned ws[4] = {u.x, u.y, u.z, u.w};
#pragma unroll
      for (int e = 0; e < 4; ++e)
        if ((ws[e] >> (sh + 8)) == pref)
          atomicAdd(&myh[(ws[e] >> sh) & 255u], 1u);
    }
    __syncthreads();
    radix_scan(hist4, st, t);
    __syncthreads();
  }

  const unsigned T = (unsigned)st[0];
  const int r = st[1];

#pragma unroll
  for (int it = 0; it < 12; ++it) {
    uint4 u = *(const uint4*)&svb[4 * (t + 256 * it)];
    unsigned ws[4] = {u.x, u.y, u.z, u.w};
#pragma unroll
    for (int e = 0; e < 4; ++e)
      if (ws[e] > T) {
        int pos = atomicAdd(&st[3], 1);
        topv[row * 32 + pos] = __uint_as_float(ws[e]);
        topi[row * 32 + pos] = 4 * (t + 256 * it) + e;
      }
  }

  int last = -1;
  const int base = 32 - r;
  for (int rd = 0; rd < r; ++rd) {
    int lm = 0x7fffffff;
#pragma unroll
    for (int it = 0; it < 12; ++it) {
      uint4 u = *(const uint4*)&svb[4 * (t + 256 * it)];
      unsigned ws[4] = {u.x, u.y, u.z, u.w};
#pragma unroll
      for (int e = 0; e < 4; ++e) {
        int j = 4 * (t + 256 * it) + e;
        if (ws[e] == T && j > last && j < lm) lm = j;
      }
    }
#pragma unroll
    for (int off = 32; off >= 1; off >>= 1) {
      int o = __shfl_xor(lm, off);
      if (o < lm) lm = o;
    }
    if ((t & 63) == 0) smin[t >> 6] = lm;
    __syncthreads();
    int g0 = smin[0] < smin[1] ? smin[0] : smin[1];
    int g1 = smin[2] < smin[3] ? smin[2] : smin[3];
    int g = g0 < g1 ? g0 : g1;
    if (t == 0) {
      topv[row * 32 + base + rd] = __uint_as_float(T);
      topi[row * 32 + base + rd] = g;
    }
    last = g;
    __syncthreads();
  }
}

// ---------------- zero + scatter ----------------
__global__ __launch_bounds__(256) void zero_kernel(float4* __restrict__ out) {
  size_t i = (size_t)blockIdx.x * 256 + threadIdx.x;
  out[i] = make_float4(0.f, 0.f, 0.f, 0.f);
}

__global__ __launch_bounds__(256) void scatter_kernel(
    const float* __restrict__ topv, const int* __restrict__ topi, float* __restrict__ out) {
  int g = blockIdx.x * 256 + threadIdx.x;
  int row = g >> 5;
  float v = 0.5f * topv[g];
  int j = topi[g];
  atomicAdd(out + (size_t)row * NROW + j, v);
  atomicAdd(out + (size_t)j * NROW + row, v);
}

// ---------------- launch ----------------
extern "C" void kernel_launch(void* const* d_in, const int* in_sizes, int n_in,
                              void* d_out, int out_size, void* d_ws, size_t ws_size,
                              hipStream_t stream)
{
  const float* X  = (const float*)d_in[0];
  const float* W1 = (const float*)d_in[1];
  const float* b1 = (const float*)d_in[2];
  const float* W2 = (const float*)d_in[3];
  const float* b2 = (const float*)d_in[4];
  const float* W3 = (const float*)d_in[5];
  const float* b3 = (const float*)d_in[6];
  float* out = (float*)d_out;

  char* ws = (char*)d_ws;
  size_t off = 0;
  auto carve = [&](size_t bytes) {
    char* p = ws + off;
    off += (bytes + 255) & ~(size_t)255;
    return (void*)p;
  };

  float* h1   = (float*)carve(4ull * NROW * HDIM);
  float* h2   = (float*)carve(4ull * NROW * HDIM);
  float* feat = (float*)carve(4ull * NROW * DFEAT);
  float* fn   = (float*)carve(4ull * NROW * DFEAT);
  float* topv = (float*)carve(4ull * NROW * 32);
  int*   topi = (int*)carve(4ull * NROW * 32);

  // MLP (chains bit-identical to round 9: K=512 single, K=1024 -> (512,512))
  gemm128<0, 1><<<dim3(HDIM / 128, NROW / 128), 256, 0, stream>>>(
      X, W1, b1, nullptr, h1, HDIM, DFEAT);
  gemm128<0, 2><<<dim3(HDIM / 128, NROW / 128), 256, 0, stream>>>(
      h1, W2, b2, nullptr, h2, HDIM, HDIM);
  gemm128<1, 2><<<dim3(DFEAT / 128, NROW / 128), 256, 0, stream>>>(
      h2, W3, b3, X, feat, DFEAT, HDIM);

  // norm + fn
  norm_fn_kernel<<<NROW / 4, 256, 0, stream>>>(feat, fn);

  // sim = relu(fn @ fn^T), symmetric: 4656 upper-tri blocks
  gemmsym<<<dim3(NB * (NB + 1) / 2), 256, 0, stream>>>(fn, out);

  // top-32 per row
  topk_kernel<<<NROW, 256, 0, stream>>>(out, topv, topi);

  // zero + symmetric scatter
  zero_kernel<<<(int)(((size_t)NROW * NROW / 4) / 256), 256, 0, stream>>>((float4*)out);
  scatter_kernel<<<(NROW * 32) / 256, 256, 0, stream>>>(topv, topi, out);
}

// Round 9
// 2860.845 us; speedup vs baseline: 1.0161x; 1.0161x over previous
//
#include <hip/hip_runtime.h>
#include <stdint.h>
#include <math.h>

typedef unsigned long long u64;

#define NROW 12288
#define DFEAT 512
#define HDIM  1024
#define NB    96   // NROW/128

// ==================================================================================
// NUMERICS CONTRACT (validated round 9, absmax 1.95e-3):
//   - every GEMM C element = single-accumulator FMA chain, k ascending, in panels
//     (512) for K=512 and (512,512) for K=1024, panels merged with one f32 add;
//   - norm = numpy classic pairwise (unchanged);
//   - top-32: exact byte-radix select (same selected SET as u64-key pop loop);
//     0.5v+0.5v symmetric scatter unchanged.
// Round 9: pre-transposed operands (XT/W*T/fnT via exact-copy transpose kernels;
// h1T/h2T written transposed by the producing GEMM). LDS tiles become linear
// k-major: staging = float4 load + ONE ds_write_b128 (no scalar writes, no XOR
// math), compute reads via hoisted base pointers + immediate offsets. Scalar
// fmaf restored (r8: pk_fma is not faster on SIMD-32). Chains bit-identical.
// ==================================================================================

// ---------------- exact 64x64 tiled transpose: out[N][M] = in[M][N] ----------
__global__ __launch_bounds__(256) void transpose_k(
    const float* __restrict__ in, float* __restrict__ out, int M, int N)
{
  __shared__ float tile[64][65];
  const int tx = threadIdx.x & 15, ty = threadIdx.x >> 4;
  const int x0 = blockIdx.x * 64, y0 = blockIdx.y * 64;
#pragma unroll
  for (int i = 0; i < 4; ++i) {
    float4 v = *(const float4*)(in + (size_t)(y0 + 4 * ty + i) * N + x0 + 4 * tx);
    tile[4 * ty + i][4 * tx + 0] = v.x;
    tile[4 * ty + i][4 * tx + 1] = v.y;
    tile[4 * ty + i][4 * tx + 2] = v.z;
    tile[4 * ty + i][4 * tx + 3] = v.w;
  }
  __syncthreads();
#pragma unroll
  for (int i = 0; i < 4; ++i) {
    float4 v = {tile[4 * tx + 0][4 * ty + i], tile[4 * tx + 1][4 * ty + i],
                tile[4 * tx + 2][4 * ty + i], tile[4 * tx + 3][4 * ty + i]};
    *(float4*)(out + (size_t)(x0 + 4 * ty + i) * M + y0 + 4 * tx) = v;
  }
}

// ---------------- MLP GEMM, pre-transposed operands, linear LDS ----------
// A-tile from AT[k][m] (lda = row stride), B-tile from BT[k][n] (ldb).
// MODE 0: C(T-layout)[h][n] = relu(acc + bias[h])     (h1T, h2T)
// MODE 1: C(normal)[n][d]  = resid + (acc + bias[d])  (feat)
// NPANEL: 1 -> K=512 single chain; 2 -> K=1024 chains (512,512), one merge add.
template <int MODE, int NPANEL>
__global__ __launch_bounds__(256, 3) void gemmT(
    const float* __restrict__ AT, const float* __restrict__ BT,
    const float* __restrict__ bias, const float* __restrict__ resid,
    float* __restrict__ C, int lda, int ldb, int K, int ldC)
{
  __shared__ float As[32][128];   // [k][m], linear
  __shared__ float Bs[32][128];   // [k][n], linear
  const int t = threadIdx.x;
  const int tn = t & 15, tm = t >> 4;
  const size_t m0 = (size_t)blockIdx.y * 128, n0 = (size_t)blockIdx.x * 128;

  float cur[2][2][4][4] = {};             // [ih][jh][i][j]
  float tot[2][2][4][4];                  // NPANEL==2 only

  const int sr = t >> 5;                  // 0..7
  const int sc = 4 * (t & 31);            // 0..124
  const float* gA = AT + (size_t)sr * lda + m0 + sc;
  const float* gB = BT + (size_t)sr * ldb + n0 + sc;
  float* wA = &As[sr][sc];
  float* wB = &Bs[sr][sc];

  const float* pa0 = &As[0][4 * tm];
  const float* pa1 = &As[0][64 + 4 * tm];
  const float* pb0 = &Bs[0][4 * tn];
  const float* pb1 = &Bs[0][64 + 4 * tn];

  for (int kt = 0; kt < K; kt += 32) {
#pragma unroll
    for (int u = 0; u < 4; ++u) {
      float4 va = *(const float4*)(gA + (size_t)(kt + 8 * u) * lda);
      float4 vb = *(const float4*)(gB + (size_t)(kt + 8 * u) * ldb);
      *(float4*)(wA + u * 8 * 128) = va;
      *(float4*)(wB + u * 8 * 128) = vb;
    }
    __syncthreads();
#pragma unroll 8
    for (int kk = 0; kk < 32; ++kk) {
      float4 a0 = *(const float4*)(pa0 + 128 * kk);
      float4 a1 = *(const float4*)(pa1 + 128 * kk);
      float4 b0 = *(const float4*)(pb0 + 128 * kk);
      float4 b1 = *(const float4*)(pb1 + 128 * kk);
      float av[2][4] = {{a0.x, a0.y, a0.z, a0.w}, {a1.x, a1.y, a1.z, a1.w}};
      float bv[2][4] = {{b0.x, b0.y, b0.z, b0.w}, {b1.x, b1.y, b1.z, b1.w}};
#pragma unroll
      for (int ih = 0; ih < 2; ++ih)
#pragma unroll
        for (int jh = 0; jh < 2; ++jh)
#pragma unroll
          for (int i = 0; i < 4; ++i)
#pragma unroll
            for (int j = 0; j < 4; ++j)
              cur[ih][jh][i][j] = fmaf(av[ih][i], bv[jh][j], cur[ih][jh][i][j]);
    }
    __syncthreads();
    if (NPANEL == 2) {
      if (kt + 32 == 512) {     // first panel ends: move, restart chain
#pragma unroll
        for (int ih = 0; ih < 2; ++ih)
#pragma unroll
          for (int jh = 0; jh < 2; ++jh)
#pragma unroll
            for (int i = 0; i < 4; ++i)
#pragma unroll
              for (int j = 0; j < 4; ++j) {
                tot[ih][jh][i][j] = cur[ih][jh][i][j];
                cur[ih][jh][i][j] = 0.f;
              }
      }
    }
  }

  if (MODE == 0) {
    // transposed write: C[h][n], h = n0+64jh+4tn+j, n-col = m0+64ih+4tm
#pragma unroll
    for (int jh = 0; jh < 2; ++jh)
#pragma unroll
      for (int j = 0; j < 4; ++j) {
        size_t hrow = n0 + 64 * jh + 4 * tn + j;
        float bb = bias[hrow];
#pragma unroll
        for (int ih = 0; ih < 2; ++ih) {
          float rv[4];
#pragma unroll
          for (int i = 0; i < 4; ++i) {
            float v = (NPANEL == 2) ? (tot[ih][jh][i][j] + cur[ih][jh][i][j])
                                    : cur[ih][jh][i][j];
            v = v + bb;
            rv[i] = v > 0.f ? v : 0.f;
          }
          float4 res = {rv[0], rv[1], rv[2], rv[3]};
          *(float4*)(C + hrow * (size_t)ldC + m0 + 64 * ih + 4 * tm) = res;
        }
      }
  } else {
    // normal write: C[n][d]
#pragma unroll
    for (int ih = 0; ih < 2; ++ih)
#pragma unroll
      for (int i = 0; i < 4; ++i) {
        size_t gm = m0 + 64 * ih + 4 * tm + i;
#pragma unroll
        for (int jh = 0; jh < 2; ++jh) {
          size_t gn = n0 + 64 * jh + 4 * tn;
          float4 rres = *(const float4*)(resid + gm * (size_t)ldC + gn);
          float rj[4] = {rres.x, rres.y, rres.z, rres.w};
          float rv[4];
#pragma unroll
          for (int j = 0; j < 4; ++j) {
            float v = (NPANEL == 2) ? (tot[ih][jh][i][j] + cur[ih][jh][i][j])
                                    : cur[ih][jh][i][j];
            v = v + bias[gn + j];
            rv[j] = rj[j] + v;
          }
          float4 res = {rv[0], rv[1], rv[2], rv[3]};
          *(float4*)(C + gm * (size_t)ldC + gn) = res;
        }
      }
  }
}

// ---------------- symmetric sim GEMM: upper-tri blocks, fnT operands ------------
__global__ __launch_bounds__(256, 4) void gemmsym(
    const float* __restrict__ FT, float* __restrict__ C)
{
  __shared__ float As[32][128];
  __shared__ float Bs[32][128];
  const int t = threadIdx.x;
  const int tn = t & 15, tm = t >> 4;

  // decode linear block -> (bi, bj), bi<=bj; S(b) = b*NB - b*(b-1)/2
  int lin = blockIdx.x;
  int bi = (int)(NB + 0.5 - sqrt((NB + 0.5) * (NB + 0.5) - 2.0 * (double)lin));
  if (bi < 0) bi = 0;
  if (bi > NB - 1) bi = NB - 1;
  while (bi + 1 <= NB - 1 && (bi + 1) * NB - ((bi + 1) * bi) / 2 <= lin) ++bi;
  while (bi * NB - (bi * (bi - 1)) / 2 > lin) --bi;
  int bj = bi + (lin - (bi * NB - (bi * (bi - 1)) / 2));

  const size_t m0 = (size_t)bi * 128, n0 = (size_t)bj * 128;

  float cur[2][2][4][4] = {};

  const int sr = t >> 5;
  const int sc = 4 * (t & 31);
  const float* gA = FT + (size_t)sr * NROW + m0 + sc;
  const float* gB = FT + (size_t)sr * NROW + n0 + sc;
  float* wA = &As[sr][sc];
  float* wB = &Bs[sr][sc];

  const float* pa0 = &As[0][4 * tm];
  const float* pa1 = &As[0][64 + 4 * tm];
  const float* pb0 = &Bs[0][4 * tn];
  const float* pb1 = &Bs[0][64 + 4 * tn];

  for (int kt = 0; kt < DFEAT; kt += 32) {
#pragma unroll
    for (int u = 0; u < 4; ++u) {
      float4 va = *(const float4*)(gA + (size_t)(kt + 8 * u) * NROW);
      float4 vb = *(const float4*)(gB + (size_t)(kt + 8 * u) * NROW);
      *(float4*)(wA + u * 8 * 128) = va;
      *(float4*)(wB + u * 8 * 128) = vb;
    }
    __syncthreads();
#pragma unroll 8
    for (int kk = 0; kk < 32; ++kk) {
      float4 a0 = *(const float4*)(pa0 + 128 * kk);
      float4 a1 = *(const float4*)(pa1 + 128 * kk);
      float4 b0 = *(const float4*)(pb0 + 128 * kk);
      float4 b1 = *(const float4*)(pb1 + 128 * kk);
      float av[2][4] = {{a0.x, a0.y, a0.z, a0.w}, {a1.x, a1.y, a1.z, a1.w}};
      float bv[2][4] = {{b0.x, b0.y, b0.z, b0.w}, {b1.x, b1.y, b1.z, b1.w}};
#pragma unroll
      for (int ih = 0; ih < 2; ++ih)
#pragma unroll
        for (int jh = 0; jh < 2; ++jh)
#pragma unroll
          for (int i = 0; i < 4; ++i)
#pragma unroll
            for (int j = 0; j < 4; ++j)
              cur[ih][jh][i][j] = fmaf(av[ih][i], bv[jh][j], cur[ih][jh][i][j]);
    }
    __syncthreads();
  }

  // relu in place
#pragma unroll
  for (int ih = 0; ih < 2; ++ih)
#pragma unroll
    for (int jh = 0; jh < 2; ++jh)
#pragma unroll
      for (int i = 0; i < 4; ++i)
#pragma unroll
        for (int j = 0; j < 4; ++j)
          cur[ih][jh][i][j] = cur[ih][jh][i][j] > 0.f ? cur[ih][jh][i][j] : 0.f;

  // normal tile write (coalesced)
#pragma unroll
  for (int ih = 0; ih < 2; ++ih)
#pragma unroll
    for (int i = 0; i < 4; ++i) {
      size_t gm = m0 + 64 * ih + 4 * tm + i;
#pragma unroll
      for (int jh = 0; jh < 2; ++jh) {
        float4 res = {cur[ih][jh][i][0], cur[ih][jh][i][1],
                      cur[ih][jh][i][2], cur[ih][jh][i][3]};
        *(float4*)(C + gm * (size_t)NROW + n0 + 64 * jh + 4 * tn) = res;
      }
    }
  // mirrored tile write (skip on diagonal blocks)
  if (bi != bj) {
#pragma unroll
    for (int jh = 0; jh < 2; ++jh)
#pragma unroll
      for (int j = 0; j < 4; ++j) {
        size_t gn = n0 + 64 * jh + 4 * tn + j;
#pragma unroll
        for (int ih = 0; ih < 2; ++ih) {
          float4 res = {cur[ih][jh][0][j], cur[ih][jh][1][j],
                        cur[ih][jh][2][j], cur[ih][jh][3][j]};
          *(float4*)(C + gn * (size_t)NROW + m0 + 64 * ih + 4 * tm) = res;
        }
      }
  }
}

// ---------------- norm + fn: numpy classic pairwise (UNCHANGED, bit-critical) -----
__global__ __launch_bounds__(256) void norm_fn_kernel(const float* __restrict__ feat,
                                                      float* __restrict__ fn) {
#pragma clang fp contract(off)
  const int row = blockIdx.x * 4 + (threadIdx.x >> 6);
  const int lane = threadIdx.x & 63;
  const float* fr = feat + (size_t)row * DFEAT;
  float r = 0.f;
  if (lane < 32) {
    const float* bp = fr + (lane >> 3) * 128 + (lane & 7);
    float x = bp[0];
    r = x * x;
#pragma unroll
    for (int i = 8; i <= 120; i += 8) {
      float x2 = bp[i];
      float s = x2 * x2;
      r = r + s;
    }
  }
  float v[32];
#pragma unroll
  for (int j = 0; j < 32; ++j) v[j] = __shfl(r, j);
  float Bv[4];
#pragma unroll
  for (int b = 0; b < 4; ++b) {
    const float* p = v + 8 * b;
    Bv[b] = ((p[0] + p[1]) + (p[2] + p[3])) + ((p[4] + p[5]) + (p[6] + p[7]));
  }
  float S = (Bv[0] + Bv[1]) + (Bv[2] + Bv[3]);
  float den = (float)sqrt((double)S) + 1e-8f;
#pragma unroll
  for (int e = 0; e < 8; ++e) {
    int d = e * 64 + lane;
    fn[(size_t)row * DFEAT + d] = fr[d] / den;
  }
}

// ---------------- per-row top-32: exact byte-radix select (privatized hist) ------
__device__ __forceinline__ void radix_scan(const unsigned int (*h4)[256], int* st, int t) {
  if (t < 64) {
    int h0 = (int)(h4[0][4 * t + 0] + h4[1][4 * t + 0] + h4[2][4 * t + 0] + h4[3][4 * t + 0]);
    int h1 = (int)(h4[0][4 * t + 1] + h4[1][4 * t + 1] + h4[2][4 * t + 1] + h4[3][4 * t + 1]);
    int h2 = (int)(h4[0][4 * t + 2] + h4[1][4 * t + 2] + h4[2][4 * t + 2] + h4[3][4 * t + 2]);
    int h3 = (int)(h4[0][4 * t + 3] + h4[1][4 * t + 3] + h4[2][4 * t + 3] + h4[3][4 * t + 3]);
    int S = h0 + h1 + h2 + h3;
#pragma unroll
    for (int off = 1; off < 64; off <<= 1) {
      int o = __shfl_down(S, off);
      if (t + off < 64) S += o;
    }
    int Sn = __shfl_down(S, 1);
    if (t == 63) Sn = 0;
    int needed = st[1];
    if (S >= needed && Sn < needed) {
      int cg = Sn, b;
      if (cg + h3 >= needed) b = 3;
      else if ((cg += h3) + h2 >= needed) b = 2;
      else if ((cg += h2) + h1 >= needed) b = 1;
      else { cg += h1; b = 0; }
      st[0] = (st[0] << 8) | (4 * t + b);
      st[1] = needed - cg;
    }
    if (t == 0 && S < needed) { st[2] = 1; st[1] = needed - S; }
  }
}

__global__ __launch_bounds__(256, 3) void topk_kernel(
    const float* __restrict__ sim, float* __restrict__ topv, int* __restrict__ topi)
{
  __shared__ __align__(16) unsigned int svb[NROW];  // 48 KiB: row value bits
  __shared__ unsigned int hist4[4][256];            // per-wave histograms
  __shared__ int st[4];
  __shared__ int smin[4];
  const int row = blockIdx.x, t = threadIdx.x;
  const float4* rp = (const float4*)(sim + (size_t)row * NROW);
  unsigned int* myh = hist4[t >> 6];

#pragma unroll
  for (int w = 0; w < 4; ++w) hist4[w][t] = 0;
  if (t == 0) { st[0] = 0; st[1] = 32; st[2] = 0; st[3] = 0; }
  __syncthreads();

#pragma unroll
  for (int it = 0; it < 12; ++it) {
    int q = t + 256 * it;
    float4 v = rp[q];
    unsigned w0 = __float_as_uint(v.x), w1 = __float_as_uint(v.y),
             w2 = __float_as_uint(v.z), w3 = __float_as_uint(v.w);
    uint4 u; u.x = w0; u.y = w1; u.z = w2; u.w = w3;
    *(uint4*)&svb[4 * q] = u;
    if (w0) atomicAdd(&myh[w0 >> 24], 1u);
    if (w1) atomicAdd(&myh[w1 >> 24], 1u);
    if (w2) atomicAdd(&myh[w2 >> 24], 1u);
    if (w3) atomicAdd(&myh[w3 >> 24], 1u);
  }
  __syncthreads();
  radix_scan(hist4, st, t);
  __syncthreads();

  for (int p = 1; p < 4; ++p) {
    if (st[2]) break;
    unsigned pref = (unsigned)st[0];
    const int sh = 24 - 8 * p;
#pragma unroll
    for (int w = 0; w < 4; ++w) hist4[w][t] = 0;
    __syncthreads();
#pragma unroll
    for (int it = 0; it < 12; ++it) {
      uint4 u = *(const uint4*)&svb[4 * (t + 256 * it)];
      unsigned ws[4] = {u.x, u.y, u.z, u.w};
#pragma unroll
      for (int e = 0; e < 4; ++e)
        if ((ws[e] >> (sh + 8)) == pref)
          atomicAdd(&myh[(ws[e] >> sh) & 255u], 1u);
    }
    __syncthreads();
    radix_scan(hist4, st, t);
    __syncthreads();
  }

  const unsigned T = (unsigned)st[0];
  const int r = st[1];

#pragma unroll
  for (int it = 0; it < 12; ++it) {
    uint4 u = *(const uint4*)&svb[4 * (t + 256 * it)];
    unsigned ws[4] = {u.x, u.y, u.z, u.w};
#pragma unroll
    for (int e = 0; e < 4; ++e)
      if (ws[e] > T) {
        int pos = atomicAdd(&st[3], 1);
        topv[row * 32 + pos] = __uint_as_float(ws[e]);
        topi[row * 32 + pos] = 4 * (t + 256 * it) + e;
      }
  }

  int last = -1;
  const int base = 32 - r;
  for (int rd = 0; rd < r; ++rd) {
    int lm = 0x7fffffff;
#pragma unroll
    for (int it = 0; it < 12; ++it) {
      uint4 u = *(const uint4*)&svb[4 * (t + 256 * it)];
      unsigned ws[4] = {u.x, u.y, u.z, u.w};
#pragma unroll
      for (int e = 0; e < 4; ++e) {
        int j = 4 * (t + 256 * it) + e;
        if (ws[e] == T && j > last && j < lm) lm = j;
      }
    }
#pragma unroll
    for (int off = 32; off >= 1; off >>= 1) {
      int o = __shfl_xor(lm, off);
      if (o < lm) lm = o;
    }
    if ((t & 63) == 0) smin[t >> 6] = lm;
    __syncthreads();
    int g0 = smin[0] < smin[1] ? smin[0] : smin[1];
    int g1 = smin[2] < smin[3] ? smin[2] : smin[3];
    int g = g0 < g1 ? g0 : g1;
    if (t == 0) {
      topv[row * 32 + base + rd] = __uint_as_float(T);
      topi[row * 32 + base + rd] = g;
    }
    last = g;
    __syncthreads();
  }
}

// ---------------- zero + scatter ----------------
__global__ __launch_bounds__(256) void zero_kernel(float4* __restrict__ out) {
  size_t i = (size_t)blockIdx.x * 256 + threadIdx.x;
  out[i] = make_float4(0.f, 0.f, 0.f, 0.f);
}

__global__ __launch_bounds__(256) void scatter_kernel(
    const float* __restrict__ topv, const int* __restrict__ topi, float* __restrict__ out) {
  int g = blockIdx.x * 256 + threadIdx.x;
  int row = g >> 5;
  float v = 0.5f * topv[g];
  int j = topi[g];
  atomicAdd(out + (size_t)row * NROW + j, v);
  atomicAdd(out + (size_t)j * NROW + row, v);
}

// ---------------- launch ----------------
extern "C" void kernel_launch(void* const* d_in, const int* in_sizes, int n_in,
                              void* d_out, int out_size, void* d_ws, size_t ws_size,
                              hipStream_t stream)
{
  const float* X  = (const float*)d_in[0];
  const float* W1 = (const float*)d_in[1];
  const float* b1 = (const float*)d_in[2];
  const float* W2 = (const float*)d_in[3];
  const float* b2 = (const float*)d_in[4];
  const float* W3 = (const float*)d_in[5];
  const float* b3 = (const float*)d_in[6];
  float* out = (float*)d_out;

  char* ws = (char*)d_ws;
  size_t off = 0;
  auto carve = [&](size_t bytes) {
    char* p = ws + off;
    off += (bytes + 255) & ~(size_t)255;
    return (void*)p;
  };

  float* h1T  = (float*)carve(4ull * NROW * HDIM);   // [1024][12288]
  float* h2T  = (float*)carve(4ull * NROW * HDIM);   // [1024][12288]
  float* feat = (float*)carve(4ull * NROW * DFEAT);  // [12288][512]
  float* fn   = (float*)carve(4ull * NROW * DFEAT);  // [12288][512]
  float* topv = (float*)carve(4ull * NROW * 32);
  int*   topi = (int*)carve(4ull * NROW * 32);

  // Aliases into currently-dead regions (ws footprint unchanged):
  float* XT  = feat;                          // [512][12288], dead before feat written
  float* W1T = fn;                            // [512][1024]
  float* W2T = fn + 512 * 1024;               // [1024][1024]
  float* W3T = fn + 512 * 1024 + 1024 * 1024; // [1024][512]   (8MB total <= 25MB)
  float* fnT = h1T;                           // [512][12288], h1T dead by then

  // exact transposes
  transpose_k<<<dim3(DFEAT / 64, NROW / 64), 256, 0, stream>>>(X, XT, NROW, DFEAT);
  transpose_k<<<dim3(DFEAT / 64, HDIM / 64), 256, 0, stream>>>(W1, W1T, HDIM, DFEAT);
  transpose_k<<<dim3(HDIM / 64, HDIM / 64), 256, 0, stream>>>(W2, W2T, HDIM, HDIM);
  transpose_k<<<dim3(HDIM / 64, DFEAT / 64), 256, 0, stream>>>(W3, W3T, DFEAT, HDIM);

  // MLP: chains bit-identical (K=512 single, K=1024 -> (512,512) register panels)
  gemmT<0, 1><<<dim3(HDIM / 128, NROW / 128), 256, 0, stream>>>(
      XT, W1T, b1, nullptr, h1T, NROW, HDIM, DFEAT, NROW);
  gemmT<0, 2><<<dim3(HDIM / 128, NROW / 128), 256, 0, stream>>>(
      h1T, W2T, b2, nullptr, h2T, NROW, HDIM, HDIM, NROW);
  gemmT<1, 2><<<dim3(DFEAT / 128, NROW / 128), 256, 0, stream>>>(
      h2T, W3T, b3, X, feat, NROW, DFEAT, HDIM, DFEAT);

  // norm + fn (fn region's W*T aliases dead now)
  norm_fn_kernel<<<NROW / 4, 256, 0, stream>>>(feat, fn);

  // fn -> fnT (h1T region dead)
  transpose_k<<<dim3(DFEAT / 64, NROW / 64), 256, 0, stream>>>(fn, fnT, NROW, DFEAT);

  // sim = relu(fn @ fn^T), symmetric: 4656 upper-tri blocks
  gemmsym<<<dim3(NB * (NB + 1) / 2), 256, 0, stream>>>(fnT, out);

  // top-32 per row
  topk_kernel<<<NROW, 256, 0, stream>>>(out, topv, topi);

  // zero + symmetric scatter
  zero_kernel<<<(int)(((size_t)NROW * NROW / 4) / 256), 256, 0, stream>>>((float4*)out);
  scatter_kernel<<<(NROW * 32) / 256, 256, 0, stream>>>(topv, topi, out);
}

// Round 10
// 2749.090 us; speedup vs baseline: 1.0574x; 1.0407x over previous
//
#include <hip/hip_runtime.h>
#include <stdint.h>
#include <math.h>

typedef unsigned long long u64;

#define NROW 12288
#define DFEAT 512
#define HDIM  1024
#define NB    96   // NROW/128

// ==================================================================================
// NUMERICS CONTRACT (validated round 9, absmax 1.95e-3):
//   - every GEMM C element = single-accumulator FMA chain, k ascending, in panels
//     (512) for K=512 and (512,512) for K=1024, panels merged with one f32 add;
//   - norm = numpy classic pairwise (unchanged);
//   - top-32: exact byte-radix select (same selected SET as u64-key pop loop);
//     0.5v+0.5v symmetric scatter unchanged.
// Round 10: revert to the best measured config (r3, 2778us: swizzled+padded LDS,
// 3-launch MLP, gemmsym lb(256,4) w/ LDS-transposed mirror) + two proven-safe wins:
// privatized per-wave topk histograms (r7, -77us) and zero_kernel FUSED into topk
// (each block zeroes its own row right after staging it to LDS — kills the
// standalone 604MB+RFO zero pass; lines are L2-hot). Chains bit-identical.
// ==================================================================================

// ---------------- MLP GEMM: 128x128 tile, 8x8/thread (2x2 groups of 4x4) ----------
template <int MODE, int NPANEL>
__global__ __launch_bounds__(256, 3) void gemm128(
    const float* __restrict__ A, const float* __restrict__ B,
    const float* __restrict__ bias, const float* __restrict__ resid,
    float* __restrict__ C, int Nn, int K)
{
  __shared__ float As[32][132];   // [k][m], XOR-swizzled m-groups
  __shared__ float Bs[32][132];   // [k][n]
  const int t = threadIdx.x;
  const int tn = t & 15, tm = t >> 4;
  const size_t m0 = (size_t)blockIdx.y * 128, n0 = (size_t)blockIdx.x * 128;

  float cur[2][2][4][4] = {};             // [ih][jh][i][j]
  float tot[2][2][4][4];                  // used only when NPANEL==2

  for (int kt = 0; kt < K; kt += 32) {
#pragma unroll
    for (int u = 0; u < 4; ++u) {
      int f = u * 256 + t;
      int r = f >> 3, c = f & 7;
      int pm = (r & 3) + 4 * ((r >> 2) ^ c);   // swizzled m-slot (bijective per k-row)
      float4 va = *(const float4*)(A + (m0 + r) * (size_t)K + kt + 4 * c);
      As[4 * c + 0][pm] = va.x; As[4 * c + 1][pm] = va.y;
      As[4 * c + 2][pm] = va.z; As[4 * c + 3][pm] = va.w;
      float4 vb = *(const float4*)(B + (n0 + r) * (size_t)K + kt + 4 * c);
      Bs[4 * c + 0][pm] = vb.x; Bs[4 * c + 1][pm] = vb.y;
      Bs[4 * c + 2][pm] = vb.z; Bs[4 * c + 3][pm] = vb.w;
    }
    __syncthreads();
#pragma unroll 4
    for (int kk = 0; kk < 32; ++kk) {
      const int key = kk >> 2;
      float4 a0 = *(const float4*)&As[kk][4 * (tm ^ key)];
      float4 a1 = *(const float4*)&As[kk][4 * (16 + (tm ^ key))];
      float4 b0 = *(const float4*)&Bs[kk][4 * (tn ^ key)];
      float4 b1 = *(const float4*)&Bs[kk][4 * (16 + (tn ^ key))];
      float av[2][4] = {{a0.x, a0.y, a0.z, a0.w}, {a1.x, a1.y, a1.z, a1.w}};
      float bv[2][4] = {{b0.x, b0.y, b0.z, b0.w}, {b1.x, b1.y, b1.z, b1.w}};
#pragma unroll
      for (int ih = 0; ih < 2; ++ih)
#pragma unroll
        for (int jh = 0; jh < 2; ++jh)
#pragma unroll
          for (int i = 0; i < 4; ++i)
#pragma unroll
            for (int j = 0; j < 4; ++j)
              cur[ih][jh][i][j] = fmaf(av[ih][i], bv[jh][j], cur[ih][jh][i][j]);
    }
    __syncthreads();
    if (NPANEL == 2) {
      int ke = kt + 32;
      if (ke == 512) {          // first panel ends: move, restart chain
#pragma unroll
        for (int ih = 0; ih < 2; ++ih)
#pragma unroll
          for (int jh = 0; jh < 2; ++jh)
#pragma unroll
            for (int i = 0; i < 4; ++i)
#pragma unroll
              for (int j = 0; j < 4; ++j) {
                tot[ih][jh][i][j] = cur[ih][jh][i][j];
                cur[ih][jh][i][j] = 0.f;
              }
      }
    }
  }
#pragma unroll
  for (int ih = 0; ih < 2; ++ih)
#pragma unroll
    for (int i = 0; i < 4; ++i) {
      size_t gm = m0 + 64 * ih + 4 * tm + i;
#pragma unroll
      for (int jh = 0; jh < 2; ++jh) {
        size_t gn = n0 + 64 * jh + 4 * tn;
        float rv[4];
#pragma unroll
        for (int j = 0; j < 4; ++j) {
          float v = (NPANEL == 2) ? (tot[ih][jh][i][j] + cur[ih][jh][i][j])
                                  : cur[ih][jh][i][j];
          v = v + bias[gn + j];
          if (MODE == 0) {
            v = v > 0.f ? v : 0.f;
          } else {
            v = resid[gm * (size_t)Nn + gn + j] + v;
          }
          rv[j] = v;
        }
        float4 res = {rv[0], rv[1], rv[2], rv[3]};
        *(float4*)(C + gm * (size_t)Nn + gn) = res;
      }
    }
}

// ---------------- symmetric sim GEMM: upper-tri blocks, write tile + mirror -------
// Mirror path: LDS float4-transpose (XOR-swizzled) -> coalesced 64B-segment stores.
__global__ __launch_bounds__(256, 4) void gemmsym(
    const float* __restrict__ F, float* __restrict__ C)
{
  __shared__ __align__(16) char shraw[33792];
  float (*As)[132] = (float (*)[132])shraw;
  float (*Bs)[132] = (float (*)[132])(shraw + 16896);
  float4* Ts = (float4*)shraw;              // aliased after k-loop (As/Bs dead)

  const int t = threadIdx.x;
  const int tn = t & 15, tm = t >> 4;

  // decode linear block -> (bi, bj), bi<=bj
  int lin = blockIdx.x;
  int bi = (int)(NB + 0.5 - sqrt((NB + 0.5) * (NB + 0.5) - 2.0 * (double)lin));
  if (bi < 0) bi = 0;
  if (bi > NB - 1) bi = NB - 1;
  while (bi + 1 <= NB - 1 && (bi + 1) * NB - ((bi + 1) * bi) / 2 <= lin) ++bi;
  while (bi * NB - (bi * (bi - 1)) / 2 > lin) --bi;
  int bj = bi + (lin - (bi * NB - (bi * (bi - 1)) / 2));

  const size_t m0 = (size_t)bi * 128, n0 = (size_t)bj * 128;

  float cur[2][2][4][4] = {};

  for (int kt = 0; kt < DFEAT; kt += 32) {
#pragma unroll
    for (int u = 0; u < 4; ++u) {
      int f = u * 256 + t;
      int r = f >> 3, c = f & 7;
      int pm = (r & 3) + 4 * ((r >> 2) ^ c);
      float4 va = *(const float4*)(F + (m0 + r) * (size_t)DFEAT + kt + 4 * c);
      As[4 * c + 0][pm] = va.x; As[4 * c + 1][pm] = va.y;
      As[4 * c + 2][pm] = va.z; As[4 * c + 3][pm] = va.w;
      float4 vb = *(const float4*)(F + (n0 + r) * (size_t)DFEAT + kt + 4 * c);
      Bs[4 * c + 0][pm] = vb.x; Bs[4 * c + 1][pm] = vb.y;
      Bs[4 * c + 2][pm] = vb.z; Bs[4 * c + 3][pm] = vb.w;
    }
    __syncthreads();
#pragma unroll 4
    for (int kk = 0; kk < 32; ++kk) {
      const int key = kk >> 2;
      float4 a0 = *(const float4*)&As[kk][4 * (tm ^ key)];
      float4 a1 = *(const float4*)&As[kk][4 * (16 + (tm ^ key))];
      float4 b0 = *(const float4*)&Bs[kk][4 * (tn ^ key)];
      float4 b1 = *(const float4*)&Bs[kk][4 * (16 + (tn ^ key))];
      float av[2][4] = {{a0.x, a0.y, a0.z, a0.w}, {a1.x, a1.y, a1.z, a1.w}};
      float bv[2][4] = {{b0.x, b0.y, b0.z, b0.w}, {b1.x, b1.y, b1.z, b1.w}};
#pragma unroll
      for (int ih = 0; ih < 2; ++ih)
#pragma unroll
        for (int jh = 0; jh < 2; ++jh)
#pragma unroll
          for (int i = 0; i < 4; ++i)
#pragma unroll
            for (int j = 0; j < 4; ++j)
              cur[ih][jh][i][j] = fmaf(av[ih][i], bv[jh][j], cur[ih][jh][i][j]);
    }
    __syncthreads();
  }

  // relu in place
#pragma unroll
  for (int ih = 0; ih < 2; ++ih)
#pragma unroll
    for (int jh = 0; jh < 2; ++jh)
#pragma unroll
      for (int i = 0; i < 4; ++i)
#pragma unroll
        for (int j = 0; j < 4; ++j)
          cur[ih][jh][i][j] = cur[ih][jh][i][j] > 0.f ? cur[ih][jh][i][j] : 0.f;

  // normal tile write (coalesced 256B segments)
#pragma unroll
  for (int ih = 0; ih < 2; ++ih)
#pragma unroll
    for (int i = 0; i < 4; ++i) {
      size_t gm = m0 + 64 * ih + 4 * tm + i;
#pragma unroll
      for (int jh = 0; jh < 2; ++jh) {
        float4 res = {cur[ih][jh][i][0], cur[ih][jh][i][1],
                      cur[ih][jh][i][2], cur[ih][jh][i][3]};
        *(float4*)(C + gm * (size_t)NROW + n0 + 64 * jh + 4 * tn) = res;
      }
    }

  // mirrored tile: LDS transpose (64 rows per jh-chunk), then coalesced stores
  if (bi != bj) {
#pragma unroll
    for (int jh = 0; jh < 2; ++jh) {
      __syncthreads();   // previous chunk reads (or k-loop/As reads) complete
#pragma unroll
      for (int ih = 0; ih < 2; ++ih)
#pragma unroll
        for (int j = 0; j < 4; ++j) {
          int rowl = 4 * tn + j;              // mirror-row within chunk, 0..63
          int slot = 16 * ih + tm;            // float4-slot along mirror row, 0..31
          int phys = slot ^ (rowl >> 2);      // conflict-free swizzle
          Ts[rowl * 32 + phys] =
              make_float4(cur[ih][jh][0][j], cur[ih][jh][1][j],
                          cur[ih][jh][2][j], cur[ih][jh][3][j]);
        }
      __syncthreads();
      {
        int rowr = t >> 2;                    // 0..63
        size_t gn = n0 + 64 * jh + rowr;
#pragma unroll
        for (int q = 0; q < 8; ++q) {
          int s = (t & 3) + 4 * q;            // logical slot: 64B contiguous / 4 lanes
          int phys = s ^ (rowr >> 2);
          float4 v = Ts[rowr * 32 + phys];
          *(float4*)(C + gn * (size_t)NROW + m0 + 4 * s) = v;
        }
      }
    }
  }
}

// ---------------- norm + fn: numpy classic pairwise (UNCHANGED, bit-critical) -----
__global__ __launch_bounds__(256) void norm_fn_kernel(const float* __restrict__ feat,
                                                      float* __restrict__ fn) {
#pragma clang fp contract(off)
  const int row = blockIdx.x * 4 + (threadIdx.x >> 6);
  const int lane = threadIdx.x & 63;
  const float* fr = feat + (size_t)row * DFEAT;
  float r = 0.f;
  if (lane < 32) {
    const float* bp = fr + (lane >> 3) * 128 + (lane & 7);
    float x = bp[0];
    r = x * x;
#pragma unroll
    for (int i = 8; i <= 120; i += 8) {
      float x2 = bp[i];
      float s = x2 * x2;
      r = r + s;
    }
  }
  float v[32];
#pragma unroll
  for (int j = 0; j < 32; ++j) v[j] = __shfl(r, j);
  float Bv[4];
#pragma unroll
  for (int b = 0; b < 4; ++b) {
    const float* p = v + 8 * b;
    Bv[b] = ((p[0] + p[1]) + (p[2] + p[3])) + ((p[4] + p[5]) + (p[6] + p[7]));
  }
  float S = (Bv[0] + Bv[1]) + (Bv[2] + Bv[3]);
  float den = (float)sqrt((double)S) + 1e-8f;
#pragma unroll
  for (int e = 0; e < 8; ++e) {
    int d = e * 64 + lane;
    fn[(size_t)row * DFEAT + d] = fr[d] / den;
  }
}

// ---------------- per-row top-32: exact byte-radix select + fused row-zero -------
// Privatized per-wave histograms (cosine sims concentrate in few bins; 4 copies
// cut same-address LDS atomic serialization 4x). Each block zeroes ITS OWN row
// right after staging it to LDS — replaces the standalone zero_kernel; lines are
// L2-hot from the just-completed read, so the store pays no cold RFO.
__device__ __forceinline__ void radix_scan(const unsigned int (*h4)[256], int* st, int t) {
  if (t < 64) {
    int h0 = (int)(h4[0][4 * t + 0] + h4[1][4 * t + 0] + h4[2][4 * t + 0] + h4[3][4 * t + 0]);
    int h1 = (int)(h4[0][4 * t + 1] + h4[1][4 * t + 1] + h4[2][4 * t + 1] + h4[3][4 * t + 1]);
    int h2 = (int)(h4[0][4 * t + 2] + h4[1][4 * t + 2] + h4[2][4 * t + 2] + h4[3][4 * t + 2]);
    int h3 = (int)(h4[0][4 * t + 3] + h4[1][4 * t + 3] + h4[2][4 * t + 3] + h4[3][4 * t + 3]);
    int S = h0 + h1 + h2 + h3;
#pragma unroll
    for (int off = 1; off < 64; off <<= 1) {
      int o = __shfl_down(S, off);
      if (t + off < 64) S += o;
    }
    int Sn = __shfl_down(S, 1);
    if (t == 63) Sn = 0;
    int needed = st[1];
    if (S >= needed && Sn < needed) {
      int cg = Sn, b;
      if (cg + h3 >= needed) b = 3;
      else if ((cg += h3) + h2 >= needed) b = 2;
      else if ((cg += h2) + h1 >= needed) b = 1;
      else { cg += h1; b = 0; }
      st[0] = (st[0] << 8) | (4 * t + b);
      st[1] = needed - cg;
    }
    if (t == 0 && S < needed) { st[2] = 1; st[1] = needed - S; }
  }
}

__global__ __launch_bounds__(256, 3) void topk_kernel(
    float* __restrict__ sim, float* __restrict__ topv, int* __restrict__ topi)
{
  __shared__ __align__(16) unsigned int svb[NROW];  // 48 KiB: row value bits
  __shared__ unsigned int hist4[4][256];            // per-wave histograms
  __shared__ int st[4];
  __shared__ int smin[4];
  const int row = blockIdx.x, t = threadIdx.x;
  float4* rp = (float4*)(sim + (size_t)row * NROW);
  unsigned int* myh = hist4[t >> 6];

#pragma unroll
  for (int w = 0; w < 4; ++w) hist4[w][t] = 0;
  if (t == 0) { st[0] = 0; st[1] = 32; st[2] = 0; st[3] = 0; }
  __syncthreads();

  const float4 z4 = make_float4(0.f, 0.f, 0.f, 0.f);
#pragma unroll
  for (int it = 0; it < 12; ++it) {
    int q = t + 256 * it;
    float4 v = rp[q];
    unsigned w0 = __float_as_uint(v.x), w1 = __float_as_uint(v.y),
             w2 = __float_as_uint(v.z), w3 = __float_as_uint(v.w);
    uint4 u; u.x = w0; u.y = w1; u.z = w2; u.w = w3;
    *(uint4*)&svb[4 * q] = u;
    rp[q] = z4;                     // fused zero: own row, L2-hot, no cold RFO
    if (w0) atomicAdd(&myh[w0 >> 24], 1u);
    if (w1) atomicAdd(&myh[w1 >> 24], 1u);
    if (w2) atomicAdd(&myh[w2 >> 24], 1u);
    if (w3) atomicAdd(&myh[w3 >> 24], 1u);
  }
  __syncthreads();
  radix_scan(hist4, st, t);
  __syncthreads();

  for (int p = 1; p < 4; ++p) {
    if (st[2]) break;
    unsigned pref = (unsigned)st[0];
    const int sh = 24 - 8 * p;
#pragma unroll
    for (int w = 0; w < 4; ++w) hist4[w][t] = 0;
    __syncthreads();
#pragma unroll
    for (int it = 0; it < 12; ++it) {
      uint4 u = *(const uint4*)&svb[4 * (t + 256 * it)];
      unsigned ws[4] = {u.x, u.y, u.z, u.w};
#pragma unroll
      for (int e = 0; e < 4; ++e)
        if ((ws[e] >> (sh + 8)) == pref)
          atomicAdd(&myh[(ws[e] >> sh) & 255u], 1u);
    }
    __syncthreads();
    radix_scan(hist4, st, t);
    __syncthreads();
  }

  const unsigned T = (unsigned)st[0];
  const int r = st[1];

#pragma unroll
  for (int it = 0; it < 12; ++it) {
    uint4 u = *(const uint4*)&svb[4 * (t + 256 * it)];
    unsigned ws[4] = {u.x, u.y, u.z, u.w};
#pragma unroll
    for (int e = 0; e < 4; ++e)
      if (ws[e] > T) {
        int pos = atomicAdd(&st[3], 1);
        topv[row * 32 + pos] = __uint_as_float(ws[e]);
        topi[row * 32 + pos] = 4 * (t + 256 * it) + e;
      }
  }

  int last = -1;
  const int base = 32 - r;
  for (int rd = 0; rd < r; ++rd) {
    int lm = 0x7fffffff;
#pragma unroll
    for (int it = 0; it < 12; ++it) {
      uint4 u = *(const uint4*)&svb[4 * (t + 256 * it)];
      unsigned ws[4] = {u.x, u.y, u.z, u.w};
#pragma unroll
      for (int e = 0; e < 4; ++e) {
        int j = 4 * (t + 256 * it) + e;
        if (ws[e] == T && j > last && j < lm) lm = j;
      }
    }
#pragma unroll
    for (int off = 32; off >= 1; off >>= 1) {
      int o = __shfl_xor(lm, off);
      if (o < lm) lm = o;
    }
    if ((t & 63) == 0) smin[t >> 6] = lm;
    __syncthreads();
    int g0 = smin[0] < smin[1] ? smin[0] : smin[1];
    int g1 = smin[2] < smin[3] ? smin[2] : smin[3];
    int g = g0 < g1 ? g0 : g1;
    if (t == 0) {
      topv[row * 32 + base + rd] = __uint_as_float(T);
      topi[row * 32 + base + rd] = g;
    }
    last = g;
    __syncthreads();
  }
}

// ---------------- scatter ----------------
__global__ __launch_bounds__(256) void scatter_kernel(
    const float* __restrict__ topv, const int* __restrict__ topi, float* __restrict__ out) {
  int g = blockIdx.x * 256 + threadIdx.x;
  int row = g >> 5;
  float v = 0.5f * topv[g];
  int j = topi[g];
  atomicAdd(out + (size_t)row * NROW + j, v);
  atomicAdd(out + (size_t)j * NROW + row, v);
}

// ---------------- launch ----------------
extern "C" void kernel_launch(void* const* d_in, const int* in_sizes, int n_in,
                              void* d_out, int out_size, void* d_ws, size_t ws_size,
                              hipStream_t stream)
{
  const float* X  = (const float*)d_in[0];
  const float* W1 = (const float*)d_in[1];
  const float* b1 = (const float*)d_in[2];
  const float* W2 = (const float*)d_in[3];
  const float* b2 = (const float*)d_in[4];
  const float* W3 = (const float*)d_in[5];
  const float* b3 = (const float*)d_in[6];
  float* out = (float*)d_out;

  char* ws = (char*)d_ws;
  size_t off = 0;
  auto carve = [&](size_t bytes) {
    char* p = ws + off;
    off += (bytes + 255) & ~(size_t)255;
    return (void*)p;
  };

  float* h1   = (float*)carve(4ull * NROW * HDIM);
  float* h2   = (float*)carve(4ull * NROW * HDIM);
  float* feat = (float*)carve(4ull * NROW * DFEAT);
  float* fn   = (float*)carve(4ull * NROW * DFEAT);
  float* topv = (float*)carve(4ull * NROW * 32);
  int*   topi = (int*)carve(4ull * NROW * 32);

  // MLP (chains bit-identical to round 9: K=512 single, K=1024 -> (512,512))
  gemm128<0, 1><<<dim3(HDIM / 128, NROW / 128), 256, 0, stream>>>(
      X, W1, b1, nullptr, h1, HDIM, DFEAT);
  gemm128<0, 2><<<dim3(HDIM / 128, NROW / 128), 256, 0, stream>>>(
      h1, W2, b2, nullptr, h2, HDIM, HDIM);
  gemm128<1, 2><<<dim3(DFEAT / 128, NROW / 128), 256, 0, stream>>>(
      h2, W3, b3, X, feat, DFEAT, HDIM);

  // norm + fn
  norm_fn_kernel<<<NROW / 4, 256, 0, stream>>>(feat, fn);

  // sim = relu(fn @ fn^T), symmetric: 4656 upper-tri blocks
  gemmsym<<<dim3(NB * (NB + 1) / 2), 256, 0, stream>>>(fn, out);

  // top-32 per row + fused zeroing of each row
  topk_kernel<<<NROW, 256, 0, stream>>>(out, topv, topi);

  // symmetric scatter into the (now zeroed) output
  scatter_kernel<<<(NROW * 32) / 256, 256, 0, stream>>>(topv, topi, out);
}